// Round 13
// baseline (2758.697 us; speedup 1.0000x reference)
//
#include <hip/hip_runtime.h>

// Geodesic shooting (Hamiltonian RK4) on MI355X.
// dyn(s) = [K@m, 2 * sum_j (mi.mj) Kij (ci - cj)], K = exp(-||ci-cj||^2), sigma=1.
// Structure: init + 4*(4 dyn + advance) = 21 dispatches.
// j-stream via wave-uniform SMEM (s_load_dwordx8: A,M adjacent) from packed buffers.
// Atomics accumulate coef*k DIRECTLY into packed stage buffers P1..P4, each
// pre-initialized to PS = packed(s); so P_n = packed(s + coef_n*k_n) is the next
// stage's input with no intermediate kernels.
// advance: s_next = PS + (P1-PS)/3 + 2/3(P2-PS) + (P3-PS)/3 + (P4-PS).

#define CN   8192
#define TPB  256
#define PTS  2
#define IGRP (TPB * PTS)    // 512 i's per block
#define NIB  (CN / IGRP)    // 16 i-groups
#define SJ   128            // j-splits
#define JC   (CN / SJ)      // 64 j's per block
#define SSZ  (2 * CN * 3)   // floats per state
#define PK   (CN * 8)       // floats per packed buffer [CN][8]

// sqrt(log2(e)): coords pre-scaled so exp(-||.||^2) == exp2(-d2_scaled).
#define CSCALE 1.2011224087864498f
#define INVCS  0.8325546111576977f
#define FSCALE (2.0f / CSCALE)

// packed layout per point: {c'x,c'y,c'z,0, mx,my,mz,0}, c' = CSCALE*c.

__global__ __launch_bounds__(TPB, 8) void dyn_kernel(
    const float4* __restrict__ jp,   // P_{n-1} (packed input state)
    float* __restrict__ pout,        // P_n (atomic accumulate coef*k)
    float cg, float cf)              // cg = coef*CSCALE, cf = coef*FSCALE
{
    const int tid = threadIdx.x;
    const int i0  = blockIdx.x * IGRP + tid;
    const int i1  = i0 + TPB;

    const float4 C0 = jp[2*i0], M0 = jp[2*i0+1];   // ci' (scaled), mi
    const float4 C1 = jp[2*i1], M1 = jp[2*i1+1];

    float g0x=0.f,g0y=0.f,g0z=0.f, f0x=0.f,f0y=0.f,f0z=0.f;
    float g1x=0.f,g1y=0.f,g1z=0.f, f1x=0.f,f1y=0.f,f1z=0.f;

    const int jbeg = blockIdx.y * JC;
    const int jend = jbeg + JC;
#pragma unroll 4
    for (int j = jbeg; j < jend; ++j) {
        const float4 A = jp[2*j];       // uniform -> s_load (merged dwordx8 with M)
        const float4 M = jp[2*j+1];
        {
            const float dx = C0.x - A.x, dy = C0.y - A.y, dz = C0.z - A.z;
            const float d2 = fmaf(dx, dx, fmaf(dy, dy, dz*dz));
            const float e  = __builtin_amdgcn_exp2f(-d2);
            const float md = fmaf(M0.x, M.x, fmaf(M0.y, M.y, M0.z * M.z));
            const float w  = md * e;
            g0x = fmaf(e, M.x, g0x); g0y = fmaf(e, M.y, g0y); g0z = fmaf(e, M.z, g0z);
            f0x = fmaf(w, dx, f0x);  f0y = fmaf(w, dy, f0y);  f0z = fmaf(w, dz, f0z);
        }
        {
            const float dx = C1.x - A.x, dy = C1.y - A.y, dz = C1.z - A.z;
            const float d2 = fmaf(dx, dx, fmaf(dy, dy, dz*dz));
            const float e  = __builtin_amdgcn_exp2f(-d2);
            const float md = fmaf(M1.x, M.x, fmaf(M1.y, M.y, M1.z * M.z));
            const float w  = md * e;
            g1x = fmaf(e, M.x, g1x); g1y = fmaf(e, M.y, g1y); g1z = fmaf(e, M.z, g1z);
            f1x = fmaf(w, dx, f1x);  f1y = fmaf(w, dy, f1y);  f1z = fmaf(w, dz, f1z);
        }
    }

    // dc contribution: cg*g into c-slots; dm contribution: cf*f into m-slots.
    // SJ adds per address, fp32 ordering noise ~1e-6 << tolerance.
    atomicAdd(&pout[i0*8+0], cg*g0x); atomicAdd(&pout[i0*8+1], cg*g0y); atomicAdd(&pout[i0*8+2], cg*g0z);
    atomicAdd(&pout[i0*8+4], cf*f0x); atomicAdd(&pout[i0*8+5], cf*f0y); atomicAdd(&pout[i0*8+6], cf*f0z);
    atomicAdd(&pout[i1*8+0], cg*g1x); atomicAdd(&pout[i1*8+1], cg*g1y); atomicAdd(&pout[i1*8+2], cg*g1z);
    atomicAdd(&pout[i1*8+4], cf*f1x); atomicAdd(&pout[i1*8+5], cf*f1y); atomicAdd(&pout[i1*8+6], cf*f1z);
}

// s_next = PS + (P1-PS)/3 + (2/3)(P2-PS) + (P3-PS)/3 + (P4-PS); re-init all buffers,
// unpack to the output slot.  idx over [0, CN*8).
__global__ __launch_bounds__(256) void advance_kernel(
    float* __restrict__ PS, float* __restrict__ P1, float* __restrict__ P2,
    float* __restrict__ P3, float* __restrict__ P4, float* __restrict__ outslot)
{
    const int idx = blockIdx.x * 256 + threadIdx.x;
    const float ps = PS[idx];
    const float v  = ps + (P1[idx]-ps)*(1.f/3.f) + (P2[idx]-ps)*(2.f/3.f)
                        + (P3[idx]-ps)*(1.f/3.f) + (P4[idx]-ps);
    PS[idx]=v; P1[idx]=v; P2[idx]=v; P3[idx]=v; P4[idx]=v;
    const int i = idx >> 3, s = idx & 7;
    if (s < 3)                 outslot[i*3 + s]          = v * INVCS;
    else if (s >= 4 && s < 7)  outslot[CN*3 + i*3 + s-4] = v;
}

__global__ __launch_bounds__(256) void init_kernel(
    const float* __restrict__ mom, const float* __restrict__ cp,
    float* __restrict__ out,
    float* __restrict__ PS, float* __restrict__ P1, float* __restrict__ P2,
    float* __restrict__ P3, float* __restrict__ P4)
{
    const int idx = blockIdx.x * 256 + threadIdx.x;
    if (idx < 5) out[idx] = 0.25f * (float)idx;      // t_span = linspace(0,1,5)
    const int i = idx >> 3, s = idx & 7;
    float v = 0.f;
    if (s < 3) {
        const float cv = cp[i*3 + s];
        v = cv * CSCALE;
        out[5 + i*3 + s] = cv;                       // st[0][0] = c0
    } else if (s >= 4 && s < 7) {
        const float mv = mom[i*3 + (s-4)];
        v = mv;
        out[5 + CN*3 + i*3 + (s-4)] = mv;            // st[0][1] = m0
    }
    PS[idx]=v; P1[idx]=v; P2[idx]=v; P3[idx]=v; P4[idx]=v;
}

extern "C" void kernel_launch(void* const* d_in, const int* in_sizes, int n_in,
                              void* d_out, int out_size, void* d_ws, size_t ws_size,
                              hipStream_t stream)
{
    const float* mom = (const float*)d_in[0];
    const float* cp  = (const float*)d_in[1];
    float* out = (float*)d_out;
    float* ws  = (float*)d_ws;

    float* PS = ws;             // CN*8 each
    float* P1 = ws + PK;
    float* P2 = ws + 2 * PK;
    float* P3 = ws + 3 * PK;
    float* P4 = ws + 4 * PK;

    const float dt = 0.25f;

    init_kernel<<<PK / 256, 256, 0, stream>>>(mom, cp, out, PS, P1, P2, P3, P4);

    dim3 dgrid(NIB, SJ);
    for (int step = 0; step < 4; ++step) {
        float* outslot = out + 5 + (size_t)(step + 1) * SSZ;
        // stage coefs: dt/2, dt/2, dt, dt/6
        dyn_kernel<<<dgrid, TPB, 0, stream>>>((const float4*)PS, P1, 0.5f*dt*CSCALE, 0.5f*dt*FSCALE);
        dyn_kernel<<<dgrid, TPB, 0, stream>>>((const float4*)P1, P2, 0.5f*dt*CSCALE, 0.5f*dt*FSCALE);
        dyn_kernel<<<dgrid, TPB, 0, stream>>>((const float4*)P2, P3, dt*CSCALE,      dt*FSCALE);
        dyn_kernel<<<dgrid, TPB, 0, stream>>>((const float4*)P3, P4, dt/6.f*CSCALE,  dt/6.f*FSCALE);
        advance_kernel<<<PK / 256, 256, 0, stream>>>(PS, P1, P2, P3, P4, outslot);
    }
}

// Round 14
// 705.018 us; speedup vs baseline: 3.9129x; 3.9129x over previous
//
#include <hip/hip_runtime.h>

// Geodesic shooting (Hamiltonian RK4) on MI355X.
// dyn(s) = [K@m, 2 * sum_j (mi.mj) Kij (ci - cj)], K = exp(-||ci-cj||^2), sigma=1.
// Structure: init + 4*(4 dyn + advance) = 21 dispatches.
// j-stream: wave-uniform SMEM (s_load_dwordx8, A/M adjacent) from packed buffers.
// k accumulation: atomics DIRECTLY into packed stage buffers P1..P4 (pre-init to
// PS), but LDS-transposed so each atomic instruction's lanes write consecutive
// 4B addresses (r13 lesson: 32B-strided atomics = 8x write-through amplification),
// and SJ=32 (vs 128) cuts atomic count 4x. TPB=64/PTS=1 keeps 4096 blocks alive.
// advance: s_next = PS + (P1-PS)/3 + 2/3(P2-PS) + (P3-PS)/3 + (P4-PS).

#define CN   8192
#define TPB  64
#define NIB  (CN / TPB)     // 128 i-groups (1 point per thread)
#define SJ   32             // j-splits
#define JC   (CN / SJ)      // 256 j's per block
#define SSZ  (2 * CN * 3)   // floats per state
#define PK   (CN * 8)       // floats per packed buffer [CN][8]

// sqrt(log2(e)): coords pre-scaled so exp(-||.||^2) == exp2(-d2_scaled).
#define CSCALE 1.2011224087864498f
#define INVCS  0.8325546111576977f
#define FSCALE (2.0f / CSCALE)

// packed layout per point: {c'x,c'y,c'z,0, mx,my,mz,0}, c' = CSCALE*c.

__global__ __launch_bounds__(TPB, 4) void dyn_kernel(
    const float4* __restrict__ jp,   // P_{n-1} (packed input state)
    float* __restrict__ pout,        // P_n (atomic accumulate coef*k)
    float cg, float cf)              // cg = coef*CSCALE, cf = coef*FSCALE
{
    const int tid = threadIdx.x;
    const int i   = blockIdx.x * TPB + tid;

    const float4 C = jp[2*i], P = jp[2*i+1];   // ci' (scaled), mi

    float gx=0.f, gy=0.f, gz=0.f, fx=0.f, fy=0.f, fz=0.f;

    const int jbeg = blockIdx.y * JC;
    const int jend = jbeg + JC;
#pragma unroll 4
    for (int j = jbeg; j < jend; ++j) {
        const float4 A = jp[2*j];       // uniform -> s_load (merged dwordx8 with M)
        const float4 M = jp[2*j+1];
        const float dx = C.x - A.x, dy = C.y - A.y, dz = C.z - A.z;
        const float d2 = fmaf(dx, dx, fmaf(dy, dy, dz*dz));
        const float e  = __builtin_amdgcn_exp2f(-d2);
        const float md = fmaf(P.x, M.x, fmaf(P.y, M.y, P.z * M.z));
        const float w  = md * e;
        gx = fmaf(e, M.x, gx); gy = fmaf(e, M.y, gy); gz = fmaf(e, M.z, gz);
        fx = fmaf(w, dx, fx);  fy = fmaf(w, dy, fy);  fz = fmaf(w, dz, fz);
    }

    // LDS transpose so atomics are lane-consecutive 4B (r9-style, 4B/atomic).
    __shared__ float st[TPB * 8];
    st[tid*8+0] = cg*gx; st[tid*8+1] = cg*gy; st[tid*8+2] = cg*gz; st[tid*8+3] = 0.f;
    st[tid*8+4] = cf*fx; st[tid*8+5] = cf*fy; st[tid*8+6] = cf*fz; st[tid*8+7] = 0.f;
    __syncthreads();

    // 64 divides 8 => (u*64+tid)&7 == tid&7: pad-lane mask is wave-uniform per lane.
    const bool live = ((tid & 7) != 3) && ((tid & 7) != 7);
    float* base = pout + (size_t)blockIdx.x * (TPB * 8);
#pragma unroll
    for (int u = 0; u < 8; ++u) {
        if (live) atomicAdd(&base[u*TPB + tid], st[u*TPB + tid]);
    }
}

// s_next = PS + (P1-PS)/3 + (2/3)(P2-PS) + (P3-PS)/3 + (P4-PS); re-init all buffers,
// unpack to the output slot.  idx over [0, CN*8).
__global__ __launch_bounds__(256) void advance_kernel(
    float* __restrict__ PS, float* __restrict__ P1, float* __restrict__ P2,
    float* __restrict__ P3, float* __restrict__ P4, float* __restrict__ outslot)
{
    const int idx = blockIdx.x * 256 + threadIdx.x;
    const float ps = PS[idx];
    const float v  = ps + (P1[idx]-ps)*(1.f/3.f) + (P2[idx]-ps)*(2.f/3.f)
                        + (P3[idx]-ps)*(1.f/3.f) + (P4[idx]-ps);
    PS[idx]=v; P1[idx]=v; P2[idx]=v; P3[idx]=v; P4[idx]=v;
    const int i = idx >> 3, s = idx & 7;
    if (s < 3)                 outslot[i*3 + s]          = v * INVCS;
    else if (s >= 4 && s < 7)  outslot[CN*3 + i*3 + s-4] = v;
}

__global__ __launch_bounds__(256) void init_kernel(
    const float* __restrict__ mom, const float* __restrict__ cp,
    float* __restrict__ out,
    float* __restrict__ PS, float* __restrict__ P1, float* __restrict__ P2,
    float* __restrict__ P3, float* __restrict__ P4)
{
    const int idx = blockIdx.x * 256 + threadIdx.x;
    if (idx < 5) out[idx] = 0.25f * (float)idx;      // t_span = linspace(0,1,5)
    const int i = idx >> 3, s = idx & 7;
    float v = 0.f;
    if (s < 3) {
        const float cv = cp[i*3 + s];
        v = cv * CSCALE;
        out[5 + i*3 + s] = cv;                       // st[0][0] = c0
    } else if (s >= 4 && s < 7) {
        const float mv = mom[i*3 + (s-4)];
        v = mv;
        out[5 + CN*3 + i*3 + (s-4)] = mv;            // st[0][1] = m0
    }
    PS[idx]=v; P1[idx]=v; P2[idx]=v; P3[idx]=v; P4[idx]=v;
}

extern "C" void kernel_launch(void* const* d_in, const int* in_sizes, int n_in,
                              void* d_out, int out_size, void* d_ws, size_t ws_size,
                              hipStream_t stream)
{
    const float* mom = (const float*)d_in[0];
    const float* cp  = (const float*)d_in[1];
    float* out = (float*)d_out;
    float* ws  = (float*)d_ws;

    float* PS = ws;             // CN*8 each
    float* P1 = ws + PK;
    float* P2 = ws + 2 * PK;
    float* P3 = ws + 3 * PK;
    float* P4 = ws + 4 * PK;

    const float dt = 0.25f;

    init_kernel<<<PK / 256, 256, 0, stream>>>(mom, cp, out, PS, P1, P2, P3, P4);

    dim3 dgrid(NIB, SJ);
    for (int step = 0; step < 4; ++step) {
        float* outslot = out + 5 + (size_t)(step + 1) * SSZ;
        // stage coefs: dt/2, dt/2, dt, dt/6
        dyn_kernel<<<dgrid, TPB, 0, stream>>>((const float4*)PS, P1, 0.5f*dt*CSCALE, 0.5f*dt*FSCALE);
        dyn_kernel<<<dgrid, TPB, 0, stream>>>((const float4*)P1, P2, 0.5f*dt*CSCALE, 0.5f*dt*FSCALE);
        dyn_kernel<<<dgrid, TPB, 0, stream>>>((const float4*)P2, P3, dt*CSCALE,      dt*FSCALE);
        dyn_kernel<<<dgrid, TPB, 0, stream>>>((const float4*)P3, P4, dt/6.f*CSCALE,  dt/6.f*FSCALE);
        advance_kernel<<<PK / 256, 256, 0, stream>>>(PS, P1, P2, P3, P4, outslot);
    }
}

// Round 15
// 661.912 us; speedup vs baseline: 4.1678x; 1.0651x over previous
//
#include <hip/hip_runtime.h>

// Geodesic shooting (Hamiltonian RK4) on MI355X.
// dyn(s) = [K@m, 2 * sum_j (mi.mj) Kij (ci - cj)], K = exp(-||ci-cj||^2), sigma=1.
// Structure: init + 4*(4 dyn + advance) = 21 dispatches.
// j-stream: wave-uniform SMEM (s_load_dwordx8, A/M adjacent) from packed buffers
// with TPB=256/PTS=2 (r5 geometry: 32 VALU ops per uniform load — proven fastest).
// k accumulation: atomics into packed stage buffers P1..P4 (pre-init to PS),
// LDS-transposed so each atomic instruction's lanes hit consecutive 4B addresses
// (r13 lesson: 32B-strided atomics = 8x write amplification). SJ=64 keeps the
// atomic count at 3.1M/dispatch (~12.6MB).
// advance: s_next = PS + (P1-PS)/3 + 2/3(P2-PS) + (P3-PS)/3 + (P4-PS).

#define CN   8192
#define TPB  256
#define PTS  2
#define IGRP (TPB * PTS)    // 512 i's per block
#define NIB  (CN / IGRP)    // 16 i-groups
#define SJ   64             // j-splits
#define JC   (CN / SJ)      // 128 j's per block
#define SSZ  (2 * CN * 3)   // floats per state
#define PK   (CN * 8)       // floats per packed buffer [CN][8]

// sqrt(log2(e)): coords pre-scaled so exp(-||.||^2) == exp2(-d2_scaled).
#define CSCALE 1.2011224087864498f
#define INVCS  0.8325546111576977f
#define FSCALE (2.0f / CSCALE)

// packed layout per point: {c'x,c'y,c'z,0, mx,my,mz,0}, c' = CSCALE*c.

__global__ __launch_bounds__(TPB, 8) void dyn_kernel(
    const float4* __restrict__ jp,   // P_{n-1} (packed input state)
    float* __restrict__ pout,        // P_n (atomic accumulate coef*k)
    float cg, float cf)              // cg = coef*CSCALE, cf = coef*FSCALE
{
    const int tid = threadIdx.x;
    const int i0  = blockIdx.x * IGRP + tid;
    const int i1  = i0 + TPB;

    const float4 C0 = jp[2*i0], M0 = jp[2*i0+1];   // ci' (scaled), mi
    const float4 C1 = jp[2*i1], M1 = jp[2*i1+1];

    float g0x=0.f,g0y=0.f,g0z=0.f, f0x=0.f,f0y=0.f,f0z=0.f;
    float g1x=0.f,g1y=0.f,g1z=0.f, f1x=0.f,f1y=0.f,f1z=0.f;

    const int jbeg = blockIdx.y * JC;
    const int jend = jbeg + JC;
#pragma unroll 4
    for (int j = jbeg; j < jend; ++j) {
        const float4 A = jp[2*j];       // uniform -> s_load (merged dwordx8 with M)
        const float4 M = jp[2*j+1];
        {
            const float dx = C0.x - A.x, dy = C0.y - A.y, dz = C0.z - A.z;
            const float d2 = fmaf(dx, dx, fmaf(dy, dy, dz*dz));
            const float e  = __builtin_amdgcn_exp2f(-d2);
            const float md = fmaf(M0.x, M.x, fmaf(M0.y, M.y, M0.z * M.z));
            const float w  = md * e;
            g0x = fmaf(e, M.x, g0x); g0y = fmaf(e, M.y, g0y); g0z = fmaf(e, M.z, g0z);
            f0x = fmaf(w, dx, f0x);  f0y = fmaf(w, dy, f0y);  f0z = fmaf(w, dz, f0z);
        }
        {
            const float dx = C1.x - A.x, dy = C1.y - A.y, dz = C1.z - A.z;
            const float d2 = fmaf(dx, dx, fmaf(dy, dy, dz*dz));
            const float e  = __builtin_amdgcn_exp2f(-d2);
            const float md = fmaf(M1.x, M.x, fmaf(M1.y, M.y, M1.z * M.z));
            const float w  = md * e;
            g1x = fmaf(e, M.x, g1x); g1y = fmaf(e, M.y, g1y); g1z = fmaf(e, M.z, g1z);
            f1x = fmaf(w, dx, f1x);  f1y = fmaf(w, dy, f1y);  f1z = fmaf(w, dz, f1z);
        }
    }

    // LDS transpose so atomics are lane-consecutive 4B (4B/atomic write-through).
    __shared__ float st[IGRP * 8];
    st[tid*8+0] = cg*g0x; st[tid*8+1] = cg*g0y; st[tid*8+2] = cg*g0z; st[tid*8+3] = 0.f;
    st[tid*8+4] = cf*f0x; st[tid*8+5] = cf*f0y; st[tid*8+6] = cf*f0z; st[tid*8+7] = 0.f;
    const int t1 = tid + TPB;
    st[t1*8+0] = cg*g1x; st[t1*8+1] = cg*g1y; st[t1*8+2] = cg*g1z; st[t1*8+3] = 0.f;
    st[t1*8+4] = cf*f1x; st[t1*8+5] = cf*f1y; st[t1*8+6] = cf*f1z; st[t1*8+7] = 0.f;
    __syncthreads();

    // 256 % 8 == 0 => (u*TPB+tid)&7 == tid&7: pad-lane mask is wave-uniform per lane.
    const bool live = ((tid & 7) != 3) && ((tid & 7) != 7);
    float* base = pout + (size_t)blockIdx.x * (IGRP * 8);
#pragma unroll
    for (int u = 0; u < (IGRP * 8) / TPB; ++u) {
        if (live) atomicAdd(&base[u*TPB + tid], st[u*TPB + tid]);
    }
}

// s_next = PS + (P1-PS)/3 + (2/3)(P2-PS) + (P3-PS)/3 + (P4-PS); re-init all buffers,
// unpack to the output slot.  idx over [0, CN*8).
__global__ __launch_bounds__(256) void advance_kernel(
    float* __restrict__ PS, float* __restrict__ P1, float* __restrict__ P2,
    float* __restrict__ P3, float* __restrict__ P4, float* __restrict__ outslot)
{
    const int idx = blockIdx.x * 256 + threadIdx.x;
    const float ps = PS[idx];
    const float v  = ps + (P1[idx]-ps)*(1.f/3.f) + (P2[idx]-ps)*(2.f/3.f)
                        + (P3[idx]-ps)*(1.f/3.f) + (P4[idx]-ps);
    PS[idx]=v; P1[idx]=v; P2[idx]=v; P3[idx]=v; P4[idx]=v;
    const int i = idx >> 3, s = idx & 7;
    if (s < 3)                 outslot[i*3 + s]          = v * INVCS;
    else if (s >= 4 && s < 7)  outslot[CN*3 + i*3 + s-4] = v;
}

__global__ __launch_bounds__(256) void init_kernel(
    const float* __restrict__ mom, const float* __restrict__ cp,
    float* __restrict__ out,
    float* __restrict__ PS, float* __restrict__ P1, float* __restrict__ P2,
    float* __restrict__ P3, float* __restrict__ P4)
{
    const int idx = blockIdx.x * 256 + threadIdx.x;
    if (idx < 5) out[idx] = 0.25f * (float)idx;      // t_span = linspace(0,1,5)
    const int i = idx >> 3, s = idx & 7;
    float v = 0.f;
    if (s < 3) {
        const float cv = cp[i*3 + s];
        v = cv * CSCALE;
        out[5 + i*3 + s] = cv;                       // st[0][0] = c0
    } else if (s >= 4 && s < 7) {
        const float mv = mom[i*3 + (s-4)];
        v = mv;
        out[5 + CN*3 + i*3 + (s-4)] = mv;            // st[0][1] = m0
    }
    PS[idx]=v; P1[idx]=v; P2[idx]=v; P3[idx]=v; P4[idx]=v;
}

extern "C" void kernel_launch(void* const* d_in, const int* in_sizes, int n_in,
                              void* d_out, int out_size, void* d_ws, size_t ws_size,
                              hipStream_t stream)
{
    const float* mom = (const float*)d_in[0];
    const float* cp  = (const float*)d_in[1];
    float* out = (float*)d_out;
    float* ws  = (float*)d_ws;

    float* PS = ws;             // CN*8 each
    float* P1 = ws + PK;
    float* P2 = ws + 2 * PK;
    float* P3 = ws + 3 * PK;
    float* P4 = ws + 4 * PK;

    const float dt = 0.25f;

    init_kernel<<<PK / 256, 256, 0, stream>>>(mom, cp, out, PS, P1, P2, P3, P4);

    dim3 dgrid(NIB, SJ);
    for (int step = 0; step < 4; ++step) {
        float* outslot = out + 5 + (size_t)(step + 1) * SSZ;
        // stage coefs: dt/2, dt/2, dt, dt/6
        dyn_kernel<<<dgrid, TPB, 0, stream>>>((const float4*)PS, P1, 0.5f*dt*CSCALE, 0.5f*dt*FSCALE);
        dyn_kernel<<<dgrid, TPB, 0, stream>>>((const float4*)P1, P2, 0.5f*dt*CSCALE, 0.5f*dt*FSCALE);
        dyn_kernel<<<dgrid, TPB, 0, stream>>>((const float4*)P2, P3, dt*CSCALE,      dt*FSCALE);
        dyn_kernel<<<dgrid, TPB, 0, stream>>>((const float4*)P3, P4, dt/6.f*CSCALE,  dt/6.f*FSCALE);
        advance_kernel<<<PK / 256, 256, 0, stream>>>(PS, P1, P2, P3, P4, outslot);
    }
}